// Round 13
// baseline (276.168 us; speedup 1.0000x reference)
//
#include <hip/hip_runtime.h>
#include <hip/hip_bf16.h>

#define NN 50000
#define EE 300000
#define ATOM_DIM 128
#define HID 256
#define NODE_DIM 64
#define NUM_LAYERS 3
#define GG 2000
#define LN_EPS 1e-5f
#define CSRC_CAP 704512   // >= E + 8*N (padded-to-8 bound = 700000)

typedef __attribute__((ext_vector_type(8))) short bf16x8;
typedef __attribute__((ext_vector_type(4))) float f32x4;

__device__ __forceinline__ ushort f2bf(float f) {
    __hip_bfloat16 h = __float2bfloat16(f);
    return *reinterpret_cast<ushort*>(&h);
}
__device__ __forceinline__ float bf2f(ushort u) {
    __hip_bfloat16 h = *reinterpret_cast<__hip_bfloat16*>(&u);
    return __bfloat162float(h);
}

__device__ __forceinline__ void gll16(const void* g, void* l) {
    __builtin_amdgcn_global_load_lds((const __attribute__((address_space(1))) unsigned int*)g,
                                     (__attribute__((address_space(3))) unsigned int*)l, 16, 0, 0);
}

// ---------------- fused prep kernel: branch ladder over flat grid ----------------

#define PB_CVT   6250
#define PB_WTE   32
#define PB_WTL   192
#define PB_GB    8
#define PB_CSRC  688
#define PB_CNT   49
#define PB_ZROW  1
#define PB_TOTAL (PB_CVT + PB_WTE + PB_WTL + PB_GB + PB_CSRC + PB_CNT + PB_ZROW)

__device__ __forceinline__ void wt_tile(const float* __restrict__ W, ushort* __restrict__ Wt,
                                        int K, int N, int bx, int by) {
    __shared__ float t[32][33];
    int lx = threadIdx.x & 31, ly = threadIdx.x >> 5;  // 32x8
#pragma unroll
    for (int s = 0; s < 32; s += 8)
        t[ly + s][lx] = W[(size_t)(by * 32 + ly + s) * N + bx * 32 + lx];
    __syncthreads();
#pragma unroll
    for (int s = 0; s < 32; s += 8)
        Wt[(size_t)(bx * 32 + ly + s) * K + by * 32 + lx] = f2bf(t[lx][ly + s]);
}

__global__ __launch_bounds__(256) void k_prep(const float* __restrict__ x, ushort* __restrict__ xbf,
                                              const float* __restrict__ W_enc, ushort* __restrict__ wtE,
                                              const float* __restrict__ Ws, ushort* __restrict__ wtL,
                                              const int* __restrict__ batch, int* __restrict__ gstart,
                                              int* __restrict__ cnt, int* __restrict__ csrc,
                                              ushort* __restrict__ hbf_zero_row) {
    int b = blockIdx.x;
    int tid = threadIdx.x;
    if (b < PB_CVT) {
        int i = (b * 256 + tid) * 4;
        float4 v = *(const float4*)&x[i];
        ushort4 o;
        o.x = f2bf(v.x); o.y = f2bf(v.y); o.z = f2bf(v.z); o.w = f2bf(v.w);
        *(ushort4*)&xbf[i] = o;
        return;
    }
    b -= PB_CVT;
    if (b < PB_WTE) {
        wt_tile(W_enc, wtE, ATOM_DIM, HID, b & 7, b >> 3);
        return;
    }
    b -= PB_WTE;
    if (b < PB_WTL) {
        int z = b >> 6, r = b & 63;
        wt_tile(Ws + (size_t)z * HID * HID, wtL + (size_t)z * HID * HID, HID, HID, r & 7, r >> 3);
        return;
    }
    b -= PB_WTL;
    if (b < PB_GB) {
        int g = b * 256 + tid;
        if (g > GG) return;
        int lo = 0, hi = NN;
        while (lo < hi) { int mid = (lo + hi) >> 1; if (batch[mid] < g) lo = mid + 1; else hi = mid; }
        gstart[g] = lo;
        return;
    }
    b -= PB_GB;
    if (b < PB_CSRC) {
        int i = (b * 256 + tid) * 4;
        if (i < CSRC_CAP) *(int4*)&csrc[i] = make_int4(NN, NN, NN, NN);
        return;
    }
    b -= PB_CSRC;
    if (b < PB_CNT) {
        int i = (b * 256 + tid) * 4;
        if (i < NN) *(int4*)&cnt[i] = make_int4(0, 0, 0, 0);
        return;
    }
    hbf_zero_row[tid] = 0;
}

// ---------------- CSR build ----------------

__global__ __launch_bounds__(256) void k_count(const int* __restrict__ ei, int* cnt, int e_total) {
    int e = blockIdx.x * 256 + threadIdx.x;
    if (e < e_total) atomicAdd(&cnt[ei[e_total + e]], 1);
}

__global__ __launch_bounds__(256) void k_scan1(const int* __restrict__ cnt, int* __restrict__ rowp,
                                               int* __restrict__ csum, int n) {
    __shared__ int s[256];
    int tid = threadIdx.x;
    int base = blockIdx.x * 1024 + tid * 4;
    int v[4];
#pragma unroll
    for (int j = 0; j < 4; ++j) { int i = base + j; v[j] = (i < n) ? ((cnt[i] + 8) & ~7) : 0; }
    int tsum = v[0] + v[1] + v[2] + v[3];
    s[tid] = tsum;
    __syncthreads();
    for (int off = 1; off < 256; off <<= 1) {
        int t = (tid >= off) ? s[tid - off] : 0;
        __syncthreads();
        s[tid] += t;
        __syncthreads();
    }
    int excl = s[tid] - tsum;
#pragma unroll
    for (int j = 0; j < 4; ++j) { int i = base + j; if (i < n) rowp[i] = excl; excl += v[j]; }
    if (tid == 255) csum[blockIdx.x] = s[255];
}

__global__ __launch_bounds__(256) void k_scan2(int* __restrict__ rowp, int* __restrict__ fill,
                                               const int* __restrict__ csum, const int* __restrict__ cnt,
                                               float* __restrict__ dinv, int n) {
    __shared__ int soff;
    int chunk = blockIdx.x;
    if (threadIdx.x == 0) {
        int o = 0;
        for (int c = 0; c < chunk; ++c) o += csum[c];
        soff = o;
    }
    __syncthreads();
    int off = soff;
    int base = chunk * 1024 + threadIdx.x * 4;
#pragma unroll
    for (int j = 0; j < 4; ++j) {
        int i = base + j;
        if (i < n) {
            int r = rowp[i] + off;
            rowp[i] = r; fill[i] = r;
            dinv[i] = rsqrtf((float)(cnt[i] + 1));
        }
    }
    if (chunk == gridDim.x - 1 && threadIdx.x == 255) rowp[n] = off + csum[chunk];
}

__global__ __launch_bounds__(256) void k_fill(const int* __restrict__ ei, int* fill, int* __restrict__ csrc,
                                              int e_total, int n) {
    int e = blockIdx.x * 256 + threadIdx.x;
    int tot = e_total + n;
    if (e >= tot) return;
    int s, d;
    if (e < e_total) { s = ei[e]; d = ei[e_total + e]; }
    else { s = d = e - e_total; }
    int pos = atomicAdd(&fill[d], 1);
    csrc[pos] = s;
}

// ---------------- bf16 MFMA GEMM, 64x64 tile, 3-deep counted-vmcnt pipeline ----------------
// (unchanged from R12 — verified best)

template <int K>
__global__ __launch_bounds__(256) void k_gemm_p64(const ushort* __restrict__ A,
                                                  const ushort* __restrict__ Bt,
                                                  const float* __restrict__ bias,
                                                  ushort* __restrict__ Cb,
                                                  const float* __restrict__ dscale, int relu,
                                                  int M) {
    constexpr int NK = K / 32;
    __shared__ short As[3][2048];  // [buf][64 rows x 32 bf16]
    __shared__ short Bs[3][2048];
    int tid = threadIdx.x;
    int lane = tid & 63, w = tid >> 6;
    int wr = w >> 1, wc = w & 1;
    int row0 = blockIdx.y * 64, col0 = blockIdx.x * 64;

    f32x4 acc[2][2] = {};

    int r15 = lane & 15;
    int swz = ((r15 >> 1) & 3) << 3;
    int koff = ((lane >> 4) << 3) ^ swz;

    int srow = tid >> 2;
    int scg = (tid & 3) ^ ((srow >> 1) & 3);
    int ra = row0 + srow; if (ra > M - 1) ra = M - 1;
    const ushort* aB = A + (size_t)ra * K + scg * 8;
    const ushort* bB = Bt + (size_t)(col0 + srow) * K + scg * 8;
    int ldst = w * 512;

#define STAGE(buf, kk) do { int k0_ = (kk) << 5;   \
        gll16(aB + k0_, &As[buf][ldst]);           \
        gll16(bB + k0_, &Bs[buf][ldst]);           \
    } while (0)

#define COMPUTE(buf) do {                                                                  \
        bf16x8 af[2], bfr[2];                                                              \
        _Pragma("unroll")                                                                  \
        for (int mi = 0; mi < 2; ++mi)                                                     \
            af[mi] = *(const bf16x8*)&As[buf][(wr * 32 + mi * 16 + r15) * 32 + koff];      \
        _Pragma("unroll")                                                                  \
        for (int ni = 0; ni < 2; ++ni)                                                     \
            bfr[ni] = *(const bf16x8*)&Bs[buf][(wc * 32 + ni * 16 + r15) * 32 + koff];     \
        _Pragma("unroll")                                                                  \
        for (int mi = 0; mi < 2; ++mi)                                                     \
            _Pragma("unroll")                                                              \
            for (int ni = 0; ni < 2; ++ni)                                                 \
                acc[mi][ni] = __builtin_amdgcn_mfma_f32_16x16x32_bf16(af[mi], bfr[ni], acc[mi][ni], 0, 0, 0); \
    } while (0)

    STAGE(0, 0);
    STAGE(1, 1);
#pragma unroll
    for (int t = 0; t < NK; ++t) {
        if (t < NK - 1) asm volatile("s_waitcnt vmcnt(2)" ::: "memory");
        else            asm volatile("s_waitcnt vmcnt(0)" ::: "memory");
        __builtin_amdgcn_s_barrier();
        if (t + 2 < NK) STAGE((t + 2) % 3, t + 2);
        COMPUTE(t % 3);
    }

#undef STAGE
#undef COMPUTE

    int cc = lane & 15, rq = (lane >> 4) * 4;
#pragma unroll
    for (int mi = 0; mi < 2; ++mi) {
#pragma unroll
        for (int r = 0; r < 4; ++r) {
            int gr = row0 + wr * 32 + mi * 16 + rq + r;
            if (gr >= M) continue;
            float ds = dscale ? dscale[gr] : 1.0f;
#pragma unroll
            for (int ni = 0; ni < 2; ++ni) {
                int gc = col0 + wc * 32 + ni * 16 + cc;
                float v = acc[mi][ni][r];
                if (bias) v += bias[gc];
                if (relu) v = fmaxf(v, 0.f);
                Cb[(size_t)gr * HID + gc] = f2bf(v * ds);
            }
        }
    }
}

// ---------------- aggregation, 4 nodes per wave (high intra-wave MLP) ----------------
// aout[v] = dinv[v] * sum_{s in padded list} hin'[s]; lists padded to x8 with zero-row (NN).
// Each wave owns 4 nodes: up to 32 independent 8B row-gather loads in flight per lane
// (4x the single-node version). Bounds wave-uniform (readfirstlane) -> no divergence.

__global__ __launch_bounds__(256) void k_aggregate_bf(const ushort* __restrict__ hin,
                                                      const int* __restrict__ rowp,
                                                      const int* __restrict__ csrc,
                                                      const float* __restrict__ dinv,
                                                      ushort* __restrict__ aout, int n) {
    int wave = threadIdx.x >> 6, lane = threadIdx.x & 63;
    int node0 = (blockIdx.x * 4 + wave) * 4;
    if (node0 >= n) return;
    const ushort* hc = hin + lane * 4;

    int j[4], e[4];
#pragma unroll
    for (int v = 0; v < 4; ++v) {
        int nd = node0 + v; if (nd > n - 1) nd = n - 1;
        j[v] = __builtin_amdgcn_readfirstlane(rowp[nd]);
        e[v] = __builtin_amdgcn_readfirstlane(rowp[nd + 1]);
    }

    f32x4 acc[4] = {};
    for (;;) {
        ushort4 r[4][8];
#pragma unroll
        for (int v = 0; v < 4; ++v) {
            if (j[v] < e[v]) {
#pragma unroll
                for (int q = 0; q < 8; ++q) {
                    int s = csrc[j[v] + q];
                    r[v][q] = *(const ushort4*)&hc[(size_t)s * HID];
                }
            }
        }
#pragma unroll
        for (int v = 0; v < 4; ++v) {
            if (j[v] < e[v]) {
                float sx = 0.f, sy = 0.f, sz = 0.f, sw = 0.f;
#pragma unroll
                for (int q = 0; q < 8; ++q) {
                    sx += bf2f(r[v][q].x); sy += bf2f(r[v][q].y);
                    sz += bf2f(r[v][q].z); sw += bf2f(r[v][q].w);
                }
                acc[v][0] += sx; acc[v][1] += sy; acc[v][2] += sz; acc[v][3] += sw;
                j[v] += 8;
            }
        }
        if (j[0] >= e[0] && j[1] >= e[1] && j[2] >= e[2] && j[3] >= e[3]) break;
    }

#pragma unroll
    for (int v = 0; v < 4; ++v) {
        int nd = node0 + v;
        if (nd >= n) break;
        float dn = dinv[nd];
        ushort4 o;
        o.x = f2bf(dn * acc[v][0]); o.y = f2bf(dn * acc[v][1]);
        o.z = f2bf(dn * acc[v][2]); o.w = f2bf(dn * acc[v][3]);
        *(ushort4*)&aout[(size_t)nd * HID + lane * 4] = o;
    }
}

// ---------------- fused pool + projection + LayerNorm (one block per graph) ----------------

__global__ __launch_bounds__(256) void k_pool_proj_ln(const ushort* __restrict__ hbf, const int* __restrict__ gstart,
                                                      const float* __restrict__ Wp, const float* __restrict__ bp,
                                                      const float* __restrict__ gamma, const float* __restrict__ beta,
                                                      float* __restrict__ out) {
    __shared__ float mol[HID];
    __shared__ float part[4][NODE_DIM];
    int g = blockIdx.x;
    int t = threadIdx.x;
    int beg = gstart[g], end = gstart[g + 1];
    float sum = 0.f;
    for (int r = beg; r < end; ++r) sum += bf2f(hbf[(size_t)r * HID + t]);
    float inv = 1.0f / fmaxf((float)(end - beg), 1.0f);
    mol[t] = sum * inv;
    __syncthreads();
    int w = t >> 6, j = t & 63;
    float p = 0.f;
    int k0 = w * 64;
#pragma unroll 8
    for (int k = 0; k < 64; ++k) p += mol[k0 + k] * Wp[(size_t)(k0 + k) * NODE_DIM + j];
    part[w][j] = p;
    __syncthreads();
    if (t < 64) {
        float pj = part[0][j] + part[1][j] + part[2][j] + part[3][j] + bp[j];
        float s = pj;
#pragma unroll
        for (int m = 1; m < 64; m <<= 1) s += __shfl_xor(s, m);
        float mu = s * (1.0f / 64.0f);
        float d = pj - mu;
        float vs = d * d;
#pragma unroll
        for (int m = 1; m < 64; m <<= 1) vs += __shfl_xor(vs, m);
        out[(size_t)g * NODE_DIM + j] = d * rsqrtf(vs * (1.0f / 64.0f) + LN_EPS) * gamma[j] + beta[j];
    }
}

// ---------------- launch ----------------

extern "C" void kernel_launch(void* const* d_in, const int* in_sizes, int n_in,
                              void* d_out, int out_size, void* d_ws, size_t ws_size,
                              hipStream_t stream) {
    const float* x     = (const float*)d_in[0];
    const int*   ei    = (const int*)d_in[1];
    const int*   batch = (const int*)d_in[2];
    const float* W_enc = (const float*)d_in[3];
    const float* b_enc = (const float*)d_in[4];
    const float* Ws    = (const float*)d_in[5];
    const float* bs    = (const float*)d_in[6];
    const float* Wp    = (const float*)d_in[7];
    const float* bp    = (const float*)d_in[8];
    const float* gamma = (const float*)d_in[9];
    const float* beta  = (const float*)d_in[10];
    float* out = (float*)d_out;

    // workspace layout
    ushort* hbf  = (ushort*)d_ws;                        // (N+1)*HID bf16 (row N = zero row)
    ushort* abf  = hbf + (size_t)(NN + 1) * HID;         // N*HID bf16 (aggregated, dinv-prescaled)
    ushort* xbf  = abf + (size_t)NN * HID;               // N*ATOM_DIM bf16
    ushort* wtE  = xbf + (size_t)NN * ATOM_DIM;          // 256*128 (W_enc^T)
    ushort* wtL  = wtE + HID * ATOM_DIM;                 // 3 * 256*256 (Ws^T)
    float*  dinv = (float*)(wtL + (size_t)NUM_LAYERS * HID * HID);  // N
    int* cnt    = (int*)(dinv + NN);                     // N
    int* rowp   = cnt + NN;                              // N+1
    int* fill   = rowp + NN + 1;                         // N
    int* csrc   = fill + NN;                             // CSRC_CAP
    int* csum   = csrc + CSRC_CAP;                       // 64
    int* gstart = csum + 64;                             // G+1

    const int EN = EE + NN;
    const int NCH = (NN + 1023) / 1024;

    k_prep<<<PB_TOTAL, 256, 0, stream>>>(x, xbf, W_enc, wtE, Ws, wtL, batch, gstart,
                                         cnt, csrc, hbf + (size_t)NN * HID);

    k_count<<<(EE + 255) / 256, 256, 0, stream>>>(ei, cnt, EE);
    k_scan1<<<NCH, 256, 0, stream>>>(cnt, rowp, csum, NN);
    k_scan2<<<NCH, 256, 0, stream>>>(rowp, fill, csum, cnt, dinv, NN);
    k_fill<<<(EN + 255) / 256, 256, 0, stream>>>(ei, fill, csrc, EE, NN);

    dim3 ggrid(HID / 64, (NN + 63) / 64);  // (4 col-tiles, 782 row-tiles) = 3128 blocks
    const int agg_blocks = (NN + 15) / 16; // 4 nodes/wave x 4 waves = 16 nodes/block

    // atom encoder: hbf = bf16( dinv * (x @ W_enc + b_enc) )
    k_gemm_p64<ATOM_DIM><<<ggrid, 256, 0, stream>>>(xbf, wtE, b_enc, hbf, dinv, 0, NN);

    // GCN layers: agg(h') then GEMM (+bias, relu, dinv-fold except last)
    for (int l = 0; l < NUM_LAYERS; ++l) {
        k_aggregate_bf<<<agg_blocks, 256, 0, stream>>>(hbf, rowp, csrc, dinv, abf, NN);
        const float* ds = (l < NUM_LAYERS - 1) ? dinv : nullptr;
        k_gemm_p64<HID><<<ggrid, 256, 0, stream>>>(abf, wtL + (size_t)l * HID * HID,
                                                   bs + (size_t)l * HID, hbf, ds, 1, NN);
    }

    k_pool_proj_ln<<<GG, 256, 0, stream>>>(hbf, gstart, Wp, bp, gamma, beta, out);
}

// Round 14
// 268.406 us; speedup vs baseline: 1.0289x; 1.0289x over previous
//
#include <hip/hip_runtime.h>
#include <hip/hip_bf16.h>

#define NN 50000
#define EE 300000
#define ATOM_DIM 128
#define HID 256
#define NODE_DIM 64
#define NUM_LAYERS 3
#define GG 2000
#define LN_EPS 1e-5f
#define CSRC_CAP 704512   // >= E + 8*N (padded-to-8 bound = 700000)

typedef __attribute__((ext_vector_type(8))) short bf16x8;
typedef __attribute__((ext_vector_type(4))) float f32x4;

__device__ __forceinline__ ushort f2bf(float f) {
    __hip_bfloat16 h = __float2bfloat16(f);
    return *reinterpret_cast<ushort*>(&h);
}
__device__ __forceinline__ float bf2f(ushort u) {
    __hip_bfloat16 h = *reinterpret_cast<__hip_bfloat16*>(&u);
    return __bfloat162float(h);
}

__device__ __forceinline__ void gll16(const void* g, void* l) {
    __builtin_amdgcn_global_load_lds((const __attribute__((address_space(1))) unsigned int*)g,
                                     (__attribute__((address_space(3))) unsigned int*)l, 16, 0, 0);
}

// ---------------- fused prep kernel: branch ladder over flat grid ----------------

#define PB_CVT   6250
#define PB_WTE   32
#define PB_WTL   192
#define PB_GB    8
#define PB_CSRC  688
#define PB_CNT   49
#define PB_ZROW  1
#define PB_TOTAL (PB_CVT + PB_WTE + PB_WTL + PB_GB + PB_CSRC + PB_CNT + PB_ZROW)

__device__ __forceinline__ void wt_tile(const float* __restrict__ W, ushort* __restrict__ Wt,
                                        int K, int N, int bx, int by) {
    __shared__ float t[32][33];
    int lx = threadIdx.x & 31, ly = threadIdx.x >> 5;  // 32x8
#pragma unroll
    for (int s = 0; s < 32; s += 8)
        t[ly + s][lx] = W[(size_t)(by * 32 + ly + s) * N + bx * 32 + lx];
    __syncthreads();
#pragma unroll
    for (int s = 0; s < 32; s += 8)
        Wt[(size_t)(bx * 32 + ly + s) * K + by * 32 + lx] = f2bf(t[lx][ly + s]);
}

__global__ __launch_bounds__(256) void k_prep(const float* __restrict__ x, ushort* __restrict__ xbf,
                                              const float* __restrict__ W_enc, ushort* __restrict__ wtE,
                                              const float* __restrict__ Ws, ushort* __restrict__ wtL,
                                              const int* __restrict__ batch, int* __restrict__ gstart,
                                              int* __restrict__ cnt, int* __restrict__ csrc,
                                              ushort* __restrict__ hbf_zero_row) {
    int b = blockIdx.x;
    int tid = threadIdx.x;
    if (b < PB_CVT) {
        int i = (b * 256 + tid) * 4;
        float4 v = *(const float4*)&x[i];
        ushort4 o;
        o.x = f2bf(v.x); o.y = f2bf(v.y); o.z = f2bf(v.z); o.w = f2bf(v.w);
        *(ushort4*)&xbf[i] = o;
        return;
    }
    b -= PB_CVT;
    if (b < PB_WTE) {
        wt_tile(W_enc, wtE, ATOM_DIM, HID, b & 7, b >> 3);
        return;
    }
    b -= PB_WTE;
    if (b < PB_WTL) {
        int z = b >> 6, r = b & 63;
        wt_tile(Ws + (size_t)z * HID * HID, wtL + (size_t)z * HID * HID, HID, HID, r & 7, r >> 3);
        return;
    }
    b -= PB_WTL;
    if (b < PB_GB) {
        int g = b * 256 + tid;
        if (g > GG) return;
        int lo = 0, hi = NN;
        while (lo < hi) { int mid = (lo + hi) >> 1; if (batch[mid] < g) lo = mid + 1; else hi = mid; }
        gstart[g] = lo;
        return;
    }
    b -= PB_GB;
    if (b < PB_CSRC) {
        int i = (b * 256 + tid) * 4;
        if (i < CSRC_CAP) *(int4*)&csrc[i] = make_int4(NN, NN, NN, NN);
        return;
    }
    b -= PB_CSRC;
    if (b < PB_CNT) {
        int i = (b * 256 + tid) * 4;
        if (i < NN) *(int4*)&cnt[i] = make_int4(0, 0, 0, 0);
        return;
    }
    hbf_zero_row[tid] = 0;
}

// ---------------- CSR build ----------------

__global__ __launch_bounds__(256) void k_count(const int* __restrict__ ei, int* cnt, int e_total) {
    int e = blockIdx.x * 256 + threadIdx.x;
    if (e < e_total) atomicAdd(&cnt[ei[e_total + e]], 1);
}

__global__ __launch_bounds__(256) void k_scan1(const int* __restrict__ cnt, int* __restrict__ rowp,
                                               int* __restrict__ csum, int n) {
    __shared__ int s[256];
    int tid = threadIdx.x;
    int base = blockIdx.x * 1024 + tid * 4;
    int v[4];
#pragma unroll
    for (int j = 0; j < 4; ++j) { int i = base + j; v[j] = (i < n) ? ((cnt[i] + 8) & ~7) : 0; }
    int tsum = v[0] + v[1] + v[2] + v[3];
    s[tid] = tsum;
    __syncthreads();
    for (int off = 1; off < 256; off <<= 1) {
        int t = (tid >= off) ? s[tid - off] : 0;
        __syncthreads();
        s[tid] += t;
        __syncthreads();
    }
    int excl = s[tid] - tsum;
#pragma unroll
    for (int j = 0; j < 4; ++j) { int i = base + j; if (i < n) rowp[i] = excl; excl += v[j]; }
    if (tid == 255) csum[blockIdx.x] = s[255];
}

__global__ __launch_bounds__(256) void k_scan2(int* __restrict__ rowp, int* __restrict__ fill,
                                               const int* __restrict__ csum, const int* __restrict__ cnt,
                                               float* __restrict__ dinv, int n) {
    __shared__ int soff;
    int chunk = blockIdx.x;
    if (threadIdx.x == 0) {
        int o = 0;
        for (int c = 0; c < chunk; ++c) o += csum[c];
        soff = o;
    }
    __syncthreads();
    int off = soff;
    int base = chunk * 1024 + threadIdx.x * 4;
#pragma unroll
    for (int j = 0; j < 4; ++j) {
        int i = base + j;
        if (i < n) {
            int r = rowp[i] + off;
            rowp[i] = r; fill[i] = r;
            dinv[i] = rsqrtf((float)(cnt[i] + 1));
        }
    }
    if (chunk == gridDim.x - 1 && threadIdx.x == 255) rowp[n] = off + csum[chunk];
}

__global__ __launch_bounds__(256) void k_fill(const int* __restrict__ ei, int* fill, int* __restrict__ csrc,
                                              int e_total, int n) {
    int e = blockIdx.x * 256 + threadIdx.x;
    int tot = e_total + n;
    if (e >= tot) return;
    int s, d;
    if (e < e_total) { s = ei[e]; d = ei[e_total + e]; }
    else { s = d = e - e_total; }
    int pos = atomicAdd(&fill[d], 1);
    csrc[pos] = s;
}

// ---------------- bf16 MFMA GEMM, 64x64 tile, 3-deep counted-vmcnt pipeline ----------------
// (unchanged from R12 — verified best)

template <int K>
__global__ __launch_bounds__(256) void k_gemm_p64(const ushort* __restrict__ A,
                                                  const ushort* __restrict__ Bt,
                                                  const float* __restrict__ bias,
                                                  ushort* __restrict__ Cb,
                                                  const float* __restrict__ dscale, int relu,
                                                  int M) {
    constexpr int NK = K / 32;
    __shared__ short As[3][2048];  // [buf][64 rows x 32 bf16]
    __shared__ short Bs[3][2048];
    int tid = threadIdx.x;
    int lane = tid & 63, w = tid >> 6;
    int wr = w >> 1, wc = w & 1;
    int row0 = blockIdx.y * 64, col0 = blockIdx.x * 64;

    f32x4 acc[2][2] = {};

    int r15 = lane & 15;
    int swz = ((r15 >> 1) & 3) << 3;
    int koff = ((lane >> 4) << 3) ^ swz;

    int srow = tid >> 2;
    int scg = (tid & 3) ^ ((srow >> 1) & 3);
    int ra = row0 + srow; if (ra > M - 1) ra = M - 1;
    const ushort* aB = A + (size_t)ra * K + scg * 8;
    const ushort* bB = Bt + (size_t)(col0 + srow) * K + scg * 8;
    int ldst = w * 512;

#define STAGE(buf, kk) do { int k0_ = (kk) << 5;   \
        gll16(aB + k0_, &As[buf][ldst]);           \
        gll16(bB + k0_, &Bs[buf][ldst]);           \
    } while (0)

#define COMPUTE(buf) do {                                                                  \
        bf16x8 af[2], bfr[2];                                                              \
        _Pragma("unroll")                                                                  \
        for (int mi = 0; mi < 2; ++mi)                                                     \
            af[mi] = *(const bf16x8*)&As[buf][(wr * 32 + mi * 16 + r15) * 32 + koff];      \
        _Pragma("unroll")                                                                  \
        for (int ni = 0; ni < 2; ++ni)                                                     \
            bfr[ni] = *(const bf16x8*)&Bs[buf][(wc * 32 + ni * 16 + r15) * 32 + koff];     \
        _Pragma("unroll")                                                                  \
        for (int mi = 0; mi < 2; ++mi)                                                     \
            _Pragma("unroll")                                                              \
            for (int ni = 0; ni < 2; ++ni)                                                 \
                acc[mi][ni] = __builtin_amdgcn_mfma_f32_16x16x32_bf16(af[mi], bfr[ni], acc[mi][ni], 0, 0, 0); \
    } while (0)

    STAGE(0, 0);
    STAGE(1, 1);
#pragma unroll
    for (int t = 0; t < NK; ++t) {
        if (t < NK - 1) asm volatile("s_waitcnt vmcnt(2)" ::: "memory");
        else            asm volatile("s_waitcnt vmcnt(0)" ::: "memory");
        __builtin_amdgcn_s_barrier();
        if (t + 2 < NK) STAGE((t + 2) % 3, t + 2);
        COMPUTE(t % 3);
    }

#undef STAGE
#undef COMPUTE

    int cc = lane & 15, rq = (lane >> 4) * 4;
#pragma unroll
    for (int mi = 0; mi < 2; ++mi) {
#pragma unroll
        for (int r = 0; r < 4; ++r) {
            int gr = row0 + wr * 32 + mi * 16 + rq + r;
            if (gr >= M) continue;
            float ds = dscale ? dscale[gr] : 1.0f;
#pragma unroll
            for (int ni = 0; ni < 2; ++ni) {
                int gc = col0 + wc * 32 + ni * 16 + cc;
                float v = acc[mi][ni][r];
                if (bias) v += bias[gc];
                if (relu) v = fmaxf(v, 0.f);
                Cb[(size_t)gr * HID + gc] = f2bf(v * ds);
            }
        }
    }
}

// ---------------- aggregation: 1 node/wave + wave-uniform degree fast paths ----------------
// aout[v] = dinv[v] * sum_{s in padded list} hin'[s]; lists padded to x8 with zero-row (NN).
// m==8 (~60% of nodes): straight-line 8 independent gathers (one latency round).
// m==16 (~35%): straight-line 16 independent gathers (one round instead of two).
// else: generic 8-wide loop. Branch is wave-uniform -> no divergence.

__global__ __launch_bounds__(256) void k_aggregate_bf(const ushort* __restrict__ hin,
                                                      const int* __restrict__ rowp,
                                                      const int* __restrict__ csrc,
                                                      const float* __restrict__ dinv,
                                                      ushort* __restrict__ aout, int n) {
    int wave = threadIdx.x >> 6, lane = threadIdx.x & 63;
    int node = blockIdx.x * 4 + wave;
    if (node >= n) return;
    int beg = __builtin_amdgcn_readfirstlane(rowp[node]);
    int end = __builtin_amdgcn_readfirstlane(rowp[node + 1]);
    int m = end - beg;
    const ushort* hc = hin + lane * 4;
    float4 acc = make_float4(0.f, 0.f, 0.f, 0.f);

    if (m == 8) {
        ushort4 r[8];
#pragma unroll
        for (int q = 0; q < 8; ++q) {
            int s = csrc[beg + q];
            r[q] = *(const ushort4*)&hc[(size_t)s * HID];
        }
#pragma unroll
        for (int q = 0; q < 8; ++q) {
            acc.x += bf2f(r[q].x); acc.y += bf2f(r[q].y);
            acc.z += bf2f(r[q].z); acc.w += bf2f(r[q].w);
        }
    } else if (m == 16) {
        ushort4 r[16];
#pragma unroll
        for (int q = 0; q < 16; ++q) {
            int s = csrc[beg + q];
            r[q] = *(const ushort4*)&hc[(size_t)s * HID];
        }
#pragma unroll
        for (int q = 0; q < 16; ++q) {
            acc.x += bf2f(r[q].x); acc.y += bf2f(r[q].y);
            acc.z += bf2f(r[q].z); acc.w += bf2f(r[q].w);
        }
    } else {
        for (int j = beg; j < end; j += 8) {
            ushort4 r[8];
#pragma unroll
            for (int q = 0; q < 8; ++q) {
                int s = csrc[j + q];
                r[q] = *(const ushort4*)&hc[(size_t)s * HID];
            }
#pragma unroll
            for (int q = 0; q < 8; ++q) {
                acc.x += bf2f(r[q].x); acc.y += bf2f(r[q].y);
                acc.z += bf2f(r[q].z); acc.w += bf2f(r[q].w);
            }
        }
    }

    float dn = dinv[node];
    ushort4 o;
    o.x = f2bf(dn * acc.x); o.y = f2bf(dn * acc.y);
    o.z = f2bf(dn * acc.z); o.w = f2bf(dn * acc.w);
    *(ushort4*)&aout[(size_t)node * HID + lane * 4] = o;
}

// ---------------- fused pool + projection + LayerNorm (one block per graph) ----------------

__global__ __launch_bounds__(256) void k_pool_proj_ln(const ushort* __restrict__ hbf, const int* __restrict__ gstart,
                                                      const float* __restrict__ Wp, const float* __restrict__ bp,
                                                      const float* __restrict__ gamma, const float* __restrict__ beta,
                                                      float* __restrict__ out) {
    __shared__ float mol[HID];
    __shared__ float part[4][NODE_DIM];
    int g = blockIdx.x;
    int t = threadIdx.x;
    int beg = gstart[g], end = gstart[g + 1];
    float sum = 0.f;
    for (int r = beg; r < end; ++r) sum += bf2f(hbf[(size_t)r * HID + t]);
    float inv = 1.0f / fmaxf((float)(end - beg), 1.0f);
    mol[t] = sum * inv;
    __syncthreads();
    int w = t >> 6, j = t & 63;
    float p = 0.f;
    int k0 = w * 64;
#pragma unroll 8
    for (int k = 0; k < 64; ++k) p += mol[k0 + k] * Wp[(size_t)(k0 + k) * NODE_DIM + j];
    part[w][j] = p;
    __syncthreads();
    if (t < 64) {
        float pj = part[0][j] + part[1][j] + part[2][j] + part[3][j] + bp[j];
        float s = pj;
#pragma unroll
        for (int m = 1; m < 64; m <<= 1) s += __shfl_xor(s, m);
        float mu = s * (1.0f / 64.0f);
        float d = pj - mu;
        float vs = d * d;
#pragma unroll
        for (int m = 1; m < 64; m <<= 1) vs += __shfl_xor(vs, m);
        out[(size_t)g * NODE_DIM + j] = d * rsqrtf(vs * (1.0f / 64.0f) + LN_EPS) * gamma[j] + beta[j];
    }
}

// ---------------- launch ----------------

extern "C" void kernel_launch(void* const* d_in, const int* in_sizes, int n_in,
                              void* d_out, int out_size, void* d_ws, size_t ws_size,
                              hipStream_t stream) {
    const float* x     = (const float*)d_in[0];
    const int*   ei    = (const int*)d_in[1];
    const int*   batch = (const int*)d_in[2];
    const float* W_enc = (const float*)d_in[3];
    const float* b_enc = (const float*)d_in[4];
    const float* Ws    = (const float*)d_in[5];
    const float* bs    = (const float*)d_in[6];
    const float* Wp    = (const float*)d_in[7];
    const float* bp    = (const float*)d_in[8];
    const float* gamma = (const float*)d_in[9];
    const float* beta  = (const float*)d_in[10];
    float* out = (float*)d_out;

    // workspace layout
    ushort* hbf  = (ushort*)d_ws;                        // (N+1)*HID bf16 (row N = zero row)
    ushort* abf  = hbf + (size_t)(NN + 1) * HID;         // N*HID bf16 (aggregated, dinv-prescaled)
    ushort* xbf  = abf + (size_t)NN * HID;               // N*ATOM_DIM bf16
    ushort* wtE  = xbf + (size_t)NN * ATOM_DIM;          // 256*128 (W_enc^T)
    ushort* wtL  = wtE + HID * ATOM_DIM;                 // 3 * 256*256 (Ws^T)
    float*  dinv = (float*)(wtL + (size_t)NUM_LAYERS * HID * HID);  // N
    int* cnt    = (int*)(dinv + NN);                     // N
    int* rowp   = cnt + NN;                              // N+1
    int* fill   = rowp + NN + 1;                         // N
    int* csrc   = fill + NN;                             // CSRC_CAP
    int* csum   = csrc + CSRC_CAP;                       // 64
    int* gstart = csum + 64;                             // G+1

    const int EN = EE + NN;
    const int NCH = (NN + 1023) / 1024;

    k_prep<<<PB_TOTAL, 256, 0, stream>>>(x, xbf, W_enc, wtE, Ws, wtL, batch, gstart,
                                         cnt, csrc, hbf + (size_t)NN * HID);

    k_count<<<(EE + 255) / 256, 256, 0, stream>>>(ei, cnt, EE);
    k_scan1<<<NCH, 256, 0, stream>>>(cnt, rowp, csum, NN);
    k_scan2<<<NCH, 256, 0, stream>>>(rowp, fill, csum, cnt, dinv, NN);
    k_fill<<<(EN + 255) / 256, 256, 0, stream>>>(ei, fill, csrc, EE, NN);

    dim3 ggrid(HID / 64, (NN + 63) / 64);  // (4 col-tiles, 782 row-tiles) = 3128 blocks
    const int agg_blocks = (NN + 3) / 4;   // 1 node/wave, 4 waves/block = 12500 blocks

    // atom encoder: hbf = bf16( dinv * (x @ W_enc + b_enc) )
    k_gemm_p64<ATOM_DIM><<<ggrid, 256, 0, stream>>>(xbf, wtE, b_enc, hbf, dinv, 0, NN);

    // GCN layers: agg(h') then GEMM (+bias, relu, dinv-fold except last)
    for (int l = 0; l < NUM_LAYERS; ++l) {
        k_aggregate_bf<<<agg_blocks, 256, 0, stream>>>(hbf, rowp, csrc, dinv, abf, NN);
        const float* ds = (l < NUM_LAYERS - 1) ? dinv : nullptr;
        k_gemm_p64<HID><<<ggrid, 256, 0, stream>>>(abf, wtL + (size_t)l * HID * HID,
                                                   bs + (size_t)l * HID, hbf, ds, 1, NN);
    }

    k_pool_proj_ln<<<GG, 256, 0, stream>>>(hbf, gstart, Wp, bp, gamma, beta, out);
}

// Round 15
// 246.841 us; speedup vs baseline: 1.1188x; 1.0874x over previous
//
#include <hip/hip_runtime.h>
#include <hip/hip_bf16.h>

#define NN 50000
#define EE 300000
#define ATOM_DIM 128
#define HID 256
#define NODE_DIM 64
#define NUM_LAYERS 3
#define GG 2000
#define LN_EPS 1e-5f
#define CSRC_CAP 704512   // >= E + 8*N (padded-to-8 bound = 700000)

typedef __attribute__((ext_vector_type(8))) short bf16x8;
typedef __attribute__((ext_vector_type(4))) float f32x4;

__device__ __forceinline__ ushort f2bf(float f) {
    __hip_bfloat16 h = __float2bfloat16(f);
    return *reinterpret_cast<ushort*>(&h);
}
__device__ __forceinline__ float bf2f(ushort u) {
    __hip_bfloat16 h = *reinterpret_cast<__hip_bfloat16*>(&u);
    return __bfloat162float(h);
}

__device__ __forceinline__ void gll16(const void* g, void* l) {
    __builtin_amdgcn_global_load_lds((const __attribute__((address_space(1))) unsigned int*)g,
                                     (__attribute__((address_space(3))) unsigned int*)l, 16, 0, 0);
}

// ---------------- fused prep kernel: branch ladder over flat grid ----------------

#define PB_CVT   6250
#define PB_WTE   32
#define PB_WTL   192
#define PB_GB    8
#define PB_CSRC  688
#define PB_CNT   49
#define PB_ZROW  1
#define PB_TOTAL (PB_CVT + PB_WTE + PB_WTL + PB_GB + PB_CSRC + PB_CNT + PB_ZROW)

__device__ __forceinline__ void wt_tile(const float* __restrict__ W, ushort* __restrict__ Wt,
                                        int K, int N, int bx, int by) {
    __shared__ float t[32][33];
    int lx = threadIdx.x & 31, ly = threadIdx.x >> 5;  // 32x8
#pragma unroll
    for (int s = 0; s < 32; s += 8)
        t[ly + s][lx] = W[(size_t)(by * 32 + ly + s) * N + bx * 32 + lx];
    __syncthreads();
#pragma unroll
    for (int s = 0; s < 32; s += 8)
        Wt[(size_t)(bx * 32 + ly + s) * K + by * 32 + lx] = f2bf(t[lx][ly + s]);
}

__global__ __launch_bounds__(256) void k_prep(const float* __restrict__ x, ushort* __restrict__ xbf,
                                              const float* __restrict__ W_enc, ushort* __restrict__ wtE,
                                              const float* __restrict__ Ws, ushort* __restrict__ wtL,
                                              const int* __restrict__ batch, int* __restrict__ gstart,
                                              int* __restrict__ cnt, int* __restrict__ csrc,
                                              ushort* __restrict__ hbf_zero_row) {
    int b = blockIdx.x;
    int tid = threadIdx.x;
    if (b < PB_CVT) {
        int i = (b * 256 + tid) * 4;
        float4 v = *(const float4*)&x[i];
        ushort4 o;
        o.x = f2bf(v.x); o.y = f2bf(v.y); o.z = f2bf(v.z); o.w = f2bf(v.w);
        *(ushort4*)&xbf[i] = o;
        return;
    }
    b -= PB_CVT;
    if (b < PB_WTE) {
        wt_tile(W_enc, wtE, ATOM_DIM, HID, b & 7, b >> 3);
        return;
    }
    b -= PB_WTE;
    if (b < PB_WTL) {
        int z = b >> 6, r = b & 63;
        wt_tile(Ws + (size_t)z * HID * HID, wtL + (size_t)z * HID * HID, HID, HID, r & 7, r >> 3);
        return;
    }
    b -= PB_WTL;
    if (b < PB_GB) {
        int g = b * 256 + tid;
        if (g > GG) return;
        int lo = 0, hi = NN;
        while (lo < hi) { int mid = (lo + hi) >> 1; if (batch[mid] < g) lo = mid + 1; else hi = mid; }
        gstart[g] = lo;
        return;
    }
    b -= PB_GB;
    if (b < PB_CSRC) {
        int i = (b * 256 + tid) * 4;
        if (i < CSRC_CAP) *(int4*)&csrc[i] = make_int4(NN, NN, NN, NN);
        return;
    }
    b -= PB_CSRC;
    if (b < PB_CNT) {
        int i = (b * 256 + tid) * 4;
        if (i < NN) *(int4*)&cnt[i] = make_int4(0, 0, 0, 0);
        return;
    }
    hbf_zero_row[tid] = 0;
}

// ---------------- CSR build ----------------

__global__ __launch_bounds__(256) void k_count(const int* __restrict__ ei, int* cnt, int e_total) {
    int e = blockIdx.x * 256 + threadIdx.x;
    if (e < e_total) atomicAdd(&cnt[ei[e_total + e]], 1);
}

__global__ __launch_bounds__(256) void k_scan1(const int* __restrict__ cnt, int* __restrict__ rowp,
                                               int* __restrict__ csum, int n) {
    __shared__ int s[256];
    int tid = threadIdx.x;
    int base = blockIdx.x * 1024 + tid * 4;
    int v[4];
#pragma unroll
    for (int j = 0; j < 4; ++j) { int i = base + j; v[j] = (i < n) ? ((cnt[i] + 8) & ~7) : 0; }
    int tsum = v[0] + v[1] + v[2] + v[3];
    s[tid] = tsum;
    __syncthreads();
    for (int off = 1; off < 256; off <<= 1) {
        int t = (tid >= off) ? s[tid - off] : 0;
        __syncthreads();
        s[tid] += t;
        __syncthreads();
    }
    int excl = s[tid] - tsum;
#pragma unroll
    for (int j = 0; j < 4; ++j) { int i = base + j; if (i < n) rowp[i] = excl; excl += v[j]; }
    if (tid == 255) csum[blockIdx.x] = s[255];
}

__global__ __launch_bounds__(256) void k_scan2(int* __restrict__ rowp, int* __restrict__ fill,
                                               const int* __restrict__ csum, const int* __restrict__ cnt,
                                               float* __restrict__ dinv, int n) {
    __shared__ int soff;
    int chunk = blockIdx.x;
    if (threadIdx.x == 0) {
        int o = 0;
        for (int c = 0; c < chunk; ++c) o += csum[c];
        soff = o;
    }
    __syncthreads();
    int off = soff;
    int base = chunk * 1024 + threadIdx.x * 4;
#pragma unroll
    for (int j = 0; j < 4; ++j) {
        int i = base + j;
        if (i < n) {
            int r = rowp[i] + off;
            rowp[i] = r; fill[i] = r;
            dinv[i] = rsqrtf((float)(cnt[i] + 1));
        }
    }
    if (chunk == gridDim.x - 1 && threadIdx.x == 255) rowp[n] = off + csum[chunk];
}

__global__ __launch_bounds__(256) void k_fill(const int* __restrict__ ei, int* fill, int* __restrict__ csrc,
                                              int e_total, int n) {
    int e = blockIdx.x * 256 + threadIdx.x;
    int tot = e_total + n;
    if (e >= tot) return;
    int s, d;
    if (e < e_total) { s = ei[e]; d = ei[e_total + e]; }
    else { s = d = e - e_total; }
    int pos = atomicAdd(&fill[d], 1);
    csrc[pos] = s;
}

// ---------------- bf16 MFMA GEMM, 64x64 tile, 3-deep counted-vmcnt pipeline ----------------
// + T1 XCD-aware block swizzle: flat grid 3128 = 8 XCDs x 391 works; XCD x owns works
// [x*391,(x+1)*391) in col-fastest order -> all 4 col-tiles of a row-tile run on the SAME
// XCD, so its A slab (~3.2MB) lives in that XCD's 4MB L2 instead of being pulled from L3 4x.

template <int K>
__global__ __launch_bounds__(256) void k_gemm_p64(const ushort* __restrict__ A,
                                                  const ushort* __restrict__ Bt,
                                                  const float* __restrict__ bias,
                                                  ushort* __restrict__ Cb,
                                                  const float* __restrict__ dscale, int relu,
                                                  int M) {
    constexpr int NK = K / 32;
    __shared__ short As[3][2048];  // [buf][64 rows x 32 bf16]
    __shared__ short Bs[3][2048];
    int tid = threadIdx.x;
    int lane = tid & 63, w = tid >> 6;
    int wr = w >> 1, wc = w & 1;

    // XCD swizzle (grid divisible by 8): hw id L -> xcd = L&7 gets contiguous work chunk
    int L = blockIdx.x;
    int cpx = gridDim.x >> 3;                    // works per XCD (391)
    int work = (L & 7) * cpx + (L >> 3);
    int row0 = (work >> 2) * 64, col0 = (work & 3) * 64;

    f32x4 acc[2][2] = {};

    int r15 = lane & 15;
    int swz = ((r15 >> 1) & 3) << 3;
    int koff = ((lane >> 4) << 3) ^ swz;

    int srow = tid >> 2;
    int scg = (tid & 3) ^ ((srow >> 1) & 3);
    int ra = row0 + srow; if (ra > M - 1) ra = M - 1;
    const ushort* aB = A + (size_t)ra * K + scg * 8;
    const ushort* bB = Bt + (size_t)(col0 + srow) * K + scg * 8;
    int ldst = w * 512;

#define STAGE(buf, kk) do { int k0_ = (kk) << 5;   \
        gll16(aB + k0_, &As[buf][ldst]);           \
        gll16(bB + k0_, &Bs[buf][ldst]);           \
    } while (0)

#define COMPUTE(buf) do {                                                                  \
        bf16x8 af[2], bfr[2];                                                              \
        _Pragma("unroll")                                                                  \
        for (int mi = 0; mi < 2; ++mi)                                                     \
            af[mi] = *(const bf16x8*)&As[buf][(wr * 32 + mi * 16 + r15) * 32 + koff];      \
        _Pragma("unroll")                                                                  \
        for (int ni = 0; ni < 2; ++ni)                                                     \
            bfr[ni] = *(const bf16x8*)&Bs[buf][(wc * 32 + ni * 16 + r15) * 32 + koff];     \
        _Pragma("unroll")                                                                  \
        for (int mi = 0; mi < 2; ++mi)                                                     \
            _Pragma("unroll")                                                              \
            for (int ni = 0; ni < 2; ++ni)                                                 \
                acc[mi][ni] = __builtin_amdgcn_mfma_f32_16x16x32_bf16(af[mi], bfr[ni], acc[mi][ni], 0, 0, 0); \
    } while (0)

    STAGE(0, 0);
    STAGE(1, 1);
#pragma unroll
    for (int t = 0; t < NK; ++t) {
        if (t < NK - 1) asm volatile("s_waitcnt vmcnt(2)" ::: "memory");
        else            asm volatile("s_waitcnt vmcnt(0)" ::: "memory");
        __builtin_amdgcn_s_barrier();
        if (t + 2 < NK) STAGE((t + 2) % 3, t + 2);
        COMPUTE(t % 3);
    }

#undef STAGE
#undef COMPUTE

    int cc = lane & 15, rq = (lane >> 4) * 4;
#pragma unroll
    for (int mi = 0; mi < 2; ++mi) {
#pragma unroll
        for (int r = 0; r < 4; ++r) {
            int gr = row0 + wr * 32 + mi * 16 + rq + r;
            if (gr >= M) continue;
            float ds = dscale ? dscale[gr] : 1.0f;
#pragma unroll
            for (int ni = 0; ni < 2; ++ni) {
                int gc = col0 + wc * 32 + ni * 16 + cc;
                float v = acc[mi][ni][r];
                if (bias) v += bias[gc];
                if (relu) v = fmaxf(v, 0.f);
                Cb[(size_t)gr * HID + gc] = f2bf(v * ds);
            }
        }
    }
}

// ---------------- aggregation: 1 node/wave + wave-uniform degree fast paths ----------------

__global__ __launch_bounds__(256) void k_aggregate_bf(const ushort* __restrict__ hin,
                                                      const int* __restrict__ rowp,
                                                      const int* __restrict__ csrc,
                                                      const float* __restrict__ dinv,
                                                      ushort* __restrict__ aout, int n) {
    int wave = threadIdx.x >> 6, lane = threadIdx.x & 63;
    int node = blockIdx.x * 4 + wave;
    if (node >= n) return;
    int beg = __builtin_amdgcn_readfirstlane(rowp[node]);
    int end = __builtin_amdgcn_readfirstlane(rowp[node + 1]);
    int m = end - beg;
    const ushort* hc = hin + lane * 4;
    float4 acc = make_float4(0.f, 0.f, 0.f, 0.f);

    if (m == 8) {
        ushort4 r[8];
#pragma unroll
        for (int q = 0; q < 8; ++q) {
            int s = csrc[beg + q];
            r[q] = *(const ushort4*)&hc[(size_t)s * HID];
        }
#pragma unroll
        for (int q = 0; q < 8; ++q) {
            acc.x += bf2f(r[q].x); acc.y += bf2f(r[q].y);
            acc.z += bf2f(r[q].z); acc.w += bf2f(r[q].w);
        }
    } else if (m == 16) {
        ushort4 r[16];
#pragma unroll
        for (int q = 0; q < 16; ++q) {
            int s = csrc[beg + q];
            r[q] = *(const ushort4*)&hc[(size_t)s * HID];
        }
#pragma unroll
        for (int q = 0; q < 16; ++q) {
            acc.x += bf2f(r[q].x); acc.y += bf2f(r[q].y);
            acc.z += bf2f(r[q].z); acc.w += bf2f(r[q].w);
        }
    } else {
        for (int j = beg; j < end; j += 8) {
            ushort4 r[8];
#pragma unroll
            for (int q = 0; q < 8; ++q) {
                int s = csrc[j + q];
                r[q] = *(const ushort4*)&hc[(size_t)s * HID];
            }
#pragma unroll
            for (int q = 0; q < 8; ++q) {
                acc.x += bf2f(r[q].x); acc.y += bf2f(r[q].y);
                acc.z += bf2f(r[q].z); acc.w += bf2f(r[q].w);
            }
        }
    }

    float dn = dinv[node];
    ushort4 o;
    o.x = f2bf(dn * acc.x); o.y = f2bf(dn * acc.y);
    o.z = f2bf(dn * acc.z); o.w = f2bf(dn * acc.w);
    *(ushort4*)&aout[(size_t)node * HID + lane * 4] = o;
}

// ---------------- fused pool + projection + LayerNorm (one block per graph) ----------------

__global__ __launch_bounds__(256) void k_pool_proj_ln(const ushort* __restrict__ hbf, const int* __restrict__ gstart,
                                                      const float* __restrict__ Wp, const float* __restrict__ bp,
                                                      const float* __restrict__ gamma, const float* __restrict__ beta,
                                                      float* __restrict__ out) {
    __shared__ float mol[HID];
    __shared__ float part[4][NODE_DIM];
    int g = blockIdx.x;
    int t = threadIdx.x;
    int beg = gstart[g], end = gstart[g + 1];
    float sum = 0.f;
    for (int r = beg; r < end; ++r) sum += bf2f(hbf[(size_t)r * HID + t]);
    float inv = 1.0f / fmaxf((float)(end - beg), 1.0f);
    mol[t] = sum * inv;
    __syncthreads();
    int w = t >> 6, j = t & 63;
    float p = 0.f;
    int k0 = w * 64;
#pragma unroll 8
    for (int k = 0; k < 64; ++k) p += mol[k0 + k] * Wp[(size_t)(k0 + k) * NODE_DIM + j];
    part[w][j] = p;
    __syncthreads();
    if (t < 64) {
        float pj = part[0][j] + part[1][j] + part[2][j] + part[3][j] + bp[j];
        float s = pj;
#pragma unroll
        for (int m = 1; m < 64; m <<= 1) s += __shfl_xor(s, m);
        float mu = s * (1.0f / 64.0f);
        float d = pj - mu;
        float vs = d * d;
#pragma unroll
        for (int m = 1; m < 64; m <<= 1) vs += __shfl_xor(vs, m);
        out[(size_t)g * NODE_DIM + j] = d * rsqrtf(vs * (1.0f / 64.0f) + LN_EPS) * gamma[j] + beta[j];
    }
}

// ---------------- launch ----------------

extern "C" void kernel_launch(void* const* d_in, const int* in_sizes, int n_in,
                              void* d_out, int out_size, void* d_ws, size_t ws_size,
                              hipStream_t stream) {
    const float* x     = (const float*)d_in[0];
    const int*   ei    = (const int*)d_in[1];
    const int*   batch = (const int*)d_in[2];
    const float* W_enc = (const float*)d_in[3];
    const float* b_enc = (const float*)d_in[4];
    const float* Ws    = (const float*)d_in[5];
    const float* bs    = (const float*)d_in[6];
    const float* Wp    = (const float*)d_in[7];
    const float* bp    = (const float*)d_in[8];
    const float* gamma = (const float*)d_in[9];
    const float* beta  = (const float*)d_in[10];
    float* out = (float*)d_out;

    // workspace layout
    ushort* hbf  = (ushort*)d_ws;                        // (N+1)*HID bf16 (row N = zero row)
    ushort* abf  = hbf + (size_t)(NN + 1) * HID;         // N*HID bf16 (aggregated, dinv-prescaled)
    ushort* xbf  = abf + (size_t)NN * HID;               // N*ATOM_DIM bf16
    ushort* wtE  = xbf + (size_t)NN * ATOM_DIM;          // 256*128 (W_enc^T)
    ushort* wtL  = wtE + HID * ATOM_DIM;                 // 3 * 256*256 (Ws^T)
    float*  dinv = (float*)(wtL + (size_t)NUM_LAYERS * HID * HID);  // N
    int* cnt    = (int*)(dinv + NN);                     // N
    int* rowp   = cnt + NN;                              // N+1
    int* fill   = rowp + NN + 1;                         // N
    int* csrc   = fill + NN;                             // CSRC_CAP
    int* csum   = csrc + CSRC_CAP;                       // 64
    int* gstart = csum + 64;                             // G+1

    const int EN = EE + NN;
    const int NCH = (NN + 1023) / 1024;

    k_prep<<<PB_TOTAL, 256, 0, stream>>>(x, xbf, W_enc, wtE, Ws, wtL, batch, gstart,
                                         cnt, csrc, hbf + (size_t)NN * HID);

    k_count<<<(EE + 255) / 256, 256, 0, stream>>>(ei, cnt, EE);
    k_scan1<<<NCH, 256, 0, stream>>>(cnt, rowp, csum, NN);
    k_scan2<<<NCH, 256, 0, stream>>>(rowp, fill, csum, cnt, dinv, NN);
    k_fill<<<(EN + 255) / 256, 256, 0, stream>>>(ei, fill, csrc, EE, NN);

    const int gblocks = 4 * ((NN + 63) / 64);  // 3128, divisible by 8 (XCD swizzle safe)
    const int agg_blocks = (NN + 3) / 4;       // 1 node/wave, 4 waves/block = 12500 blocks

    // atom encoder: hbf = bf16( dinv * (x @ W_enc + b_enc) )
    k_gemm_p64<ATOM_DIM><<<gblocks, 256, 0, stream>>>(xbf, wtE, b_enc, hbf, dinv, 0, NN);

    // GCN layers: agg(h') then GEMM (+bias, relu, dinv-fold except last)
    for (int l = 0; l < NUM_LAYERS; ++l) {
        k_aggregate_bf<<<agg_blocks, 256, 0, stream>>>(hbf, rowp, csrc, dinv, abf, NN);
        const float* ds = (l < NUM_LAYERS - 1) ? dinv : nullptr;
        k_gemm_p64<HID><<<gblocks, 256, 0, stream>>>(abf, wtL + (size_t)l * HID * HID,
                                                     bs + (size_t)l * HID, hbf, ds, 1, NN);
    }

    k_pool_proj_ln<<<GG, 256, 0, stream>>>(hbf, gstart, Wp, bp, gamma, beta, out);
}